// Round 1
// baseline (93.794 us; speedup 1.0000x reference)
//
#include <hip/hip_runtime.h>
#include <cmath>

// Local contrast normalization, fused single kernel.
// x: [64,512,512,1] f32. 9x9 Gaussian (separable), SAME zero padding.
// out = keep ? demeaned/sqrt(conv(demeaned^2)) : demeaned, keep = norm > 0.5.

struct W9 { float w[9]; };

#define B  64
#define HW 512
#define TS 32      // output tile
#define XT 48      // TS + 16 (x halo: +-8)
#define MT 40      // TS + 8  (demeaned region: +-4)

// padded LDS strides: multiples of 4 floats (16B align for b128),
// non-power-of-2 mod 32 to spread banks
#define XS_LD 52
#define H1_LD 44
#define D_LD  44
#define H2_LD 36

__global__ __launch_bounds__(256) void lcn_kernel(const float* __restrict__ x,
                                                  float* __restrict__ out,
                                                  W9 wts) {
    __shared__ float xs[XT][XS_LD];  // x halo tile
    __shared__ float h1[XT][H1_LD];  // horizontal conv of x   (48 x 40 valid)
    __shared__ float dd[MT][D_LD];   // demeaned               (40 x 40 valid)
    __shared__ float h2[MT][H2_LD];  // horizontal conv of d^2 (40 x 32 valid)

    const int tid = threadIdx.x;
    const int ox  = blockIdx.x * TS;
    const int oy  = blockIdx.y * TS;
    const int b   = blockIdx.z;
    const float* xb = x + (size_t)b * HW * HW;

    float w[9];
#pragma unroll
    for (int i = 0; i < 9; ++i) w[i] = wts.w[i];

    // ---- load 48x48 x halo (zero-pad outside image): 2304 = 256 * 9 ----
#pragma unroll
    for (int it = 0; it < 9; ++it) {
        int idx = tid + it * 256;
        int r = idx / XT, c = idx % XT;
        int gy = oy - 8 + r, gx = ox - 8 + c;
        float v = 0.f;
        if (gy >= 0 && gy < HW && gx >= 0 && gx < HW) v = xb[gy * HW + gx];
        xs[r][c] = v;
    }
    __syncthreads();

    // ---- h1[r][c] = sum_j w[j] * xs[r][c+j], 48 rows x 40 cols ----
    // 240 tasks: each thread does an 8-wide run (16 LDS reads -> 72 FMA)
    if (tid < 240) {
        int r = tid / 5, c0 = (tid % 5) * 8;
        float xv[16];
#pragma unroll
        for (int i = 0; i < 16; ++i) xv[i] = xs[r][c0 + i];
#pragma unroll
        for (int k = 0; k < 8; ++k) {
            float acc = 0.f;
#pragma unroll
            for (int j = 0; j < 9; ++j) acc = fmaf(w[j], xv[k + j], acc);
            h1[r][c0 + k] = acc;
        }
    }
    __syncthreads();

    // ---- m = vertical conv of h1; dd = x - m (zeroed outside image) ----
    // 40x40 outputs; 200 tasks: column c, 8-row run
    if (tid < 200) {
        int c = tid % MT, r0 = (tid / MT) * 8;
        float hv[16];
#pragma unroll
        for (int i = 0; i < 16; ++i) hv[i] = h1[r0 + i][c];
        int gx = ox - 4 + c;
        bool cin = (gx >= 0 && gx < HW);
#pragma unroll
        for (int k = 0; k < 8; ++k) {
            float acc = 0.f;
#pragma unroll
            for (int j = 0; j < 9; ++j) acc = fmaf(w[j], hv[k + j], acc);
            int r = r0 + k;
            int gy = oy - 4 + r;
            float dv = 0.f;
            if (cin && gy >= 0 && gy < HW) dv = xs[r + 4][c + 4] - acc;
            dd[r][c] = dv;
        }
    }
    __syncthreads();

    // ---- h2[r][c] = sum_j w[j] * dd[r][c+j]^2, 40 rows x 32 cols ----
    // 160 tasks
    if (tid < 160) {
        int r = tid / 4, c0 = (tid % 4) * 8;
        float dv[16];
#pragma unroll
        for (int i = 0; i < 16; ++i) { float t = dd[r][c0 + i]; dv[i] = t * t; }
#pragma unroll
        for (int k = 0; k < 8; ++k) {
            float acc = 0.f;
#pragma unroll
            for (int j = 0; j < 9; ++j) acc = fmaf(w[j], dv[k + j], acc);
            h2[r][c0 + k] = acc;
        }
    }
    __syncthreads();

    // ---- n2 = vertical conv of h2; out = keep ? d/sqrt(n2) : d ----
    // 32x32 outputs; 128 tasks: column c, 8-row run
    if (tid < 128) {
        int c = tid % TS, r0 = (tid / TS) * 8;
        float hv[16];
#pragma unroll
        for (int i = 0; i < 16; ++i) hv[i] = h2[r0 + i][c];
        float* ob = out + (size_t)b * HW * HW;
#pragma unroll
        for (int k = 0; k < 8; ++k) {
            float acc = 0.f;
#pragma unroll
            for (int j = 0; j < 9; ++j) acc = fmaf(w[j], hv[k + j], acc);
            float nrm = sqrtf(acc);
            float dc  = dd[r0 + k + 4][c + 4];
            float o   = (nrm > 0.5f) ? (dc / nrm) : dc;
            int gy = oy + r0 + k, gx = ox + c;
            ob[gy * HW + gx] = o;
        }
    }
}

static W9 make_w() {
    // matches reference: sigmah = 9/6, exponent divides by 2*sigmah = 3.0.
    // 2D weight = g1[i]*g1[j] / (sum g1)^2 -> separable w1 = g1 / sum(g1).
    double g[9], s = 0.0;
    for (int i = 0; i < 9; ++i) {
        double off = (double)i - 4.5;
        g[i] = exp(-(off * off) / 3.0);
        s += g[i];
    }
    W9 r;
    for (int i = 0; i < 9; ++i) r.w[i] = (float)(g[i] / s);
    return r;
}

extern "C" void kernel_launch(void* const* d_in, const int* in_sizes, int n_in,
                              void* d_out, int out_size, void* d_ws, size_t ws_size,
                              hipStream_t stream) {
    const float* x = (const float*)d_in[0];
    float* out = (float*)d_out;
    W9 w = make_w();
    dim3 grid(HW / TS, HW / TS, B);  // 16 x 16 x 64
    lcn_kernel<<<grid, dim3(256), 0, stream>>>(x, out, w);
}